// Round 1
// baseline (1028.333 us; speedup 1.0000x reference)
//
#include <hip/hip_runtime.h>

#define N_NODES  100000
#define N_EDGES  3200000
#define NFEAT    256
#define NHID     128
#define NCLASS   16
#define TEXT_CNT 50000

// ---------------- CSR build ----------------

__global__ void zero_int_kernel(int* __restrict__ p, int n) {
  int i = blockIdx.x * blockDim.x + threadIdx.x;
  if (i < n) p[i] = 0;
}

__global__ void count_kernel(const int* __restrict__ rows, int* __restrict__ cnt, int E) {
  int stride = gridDim.x * blockDim.x;
  for (int e = blockIdx.x * blockDim.x + threadIdx.x; e < E; e += stride)
    atomicAdd(&cnt[rows[e]], 1);
}

__global__ __launch_bounds__(1024) void scan1_kernel(const int* __restrict__ cnt,
                                                     int* __restrict__ tmp,
                                                     int* __restrict__ partials, int n) {
  __shared__ int s[1024];
  int tid = threadIdx.x;
  int i = blockIdx.x * 1024 + tid;
  int v = (i < n) ? cnt[i] : 0;
  s[tid] = v;
  __syncthreads();
  for (int off = 1; off < 1024; off <<= 1) {
    int t = (tid >= off) ? s[tid - off] : 0;
    __syncthreads();
    s[tid] += t;
    __syncthreads();
  }
  if (i < n) tmp[i] = s[tid] - v;             // exclusive within chunk
  if (tid == 1023) partials[blockIdx.x] = s[1023];
}

__global__ __launch_bounds__(128) void scan2_kernel(int* __restrict__ partials, int nchunk) {
  __shared__ int s[128];
  int tid = threadIdx.x;
  int v = (tid < nchunk) ? partials[tid] : 0;
  s[tid] = v;
  __syncthreads();
  for (int off = 1; off < 128; off <<= 1) {
    int t = (tid >= off) ? s[tid - off] : 0;
    __syncthreads();
    s[tid] += t;
    __syncthreads();
  }
  if (tid < nchunk) partials[tid] = s[tid] - v; // exclusive chunk offsets
}

__global__ __launch_bounds__(1024) void scan3_kernel(const int* __restrict__ tmp,
                                                     const int* __restrict__ partials,
                                                     int* __restrict__ row_ptr,
                                                     int* __restrict__ cursor, int n, int E) {
  int i = blockIdx.x * 1024 + threadIdx.x;
  if (i < n) {
    int v = tmp[i] + partials[blockIdx.x];
    row_ptr[i] = v;
    cursor[i] = v;
  }
  if (i == 0) row_ptr[n] = E;
}

__global__ void fill_kernel(const int* __restrict__ rows, const int* __restrict__ cols,
                            const float* __restrict__ vals, int* __restrict__ cursor,
                            int* __restrict__ ecol, float* __restrict__ evals, int E) {
  int stride = gridDim.x * blockDim.x;
  for (int e = blockIdx.x * blockDim.x + threadIdx.x; e < E; e += stride) {
    int p = atomicAdd(&cursor[rows[e]], 1);
    ecol[p] = cols[e];
    evals[p] = vals[e];
  }
}

// ---------------- FP32 tiled GEMM: C[M,N] = A[M,K] @ B[K,N] (+bias) ----------------
// BM=128, BN=128, BK=16, 256 threads, 8x8 per thread.

__global__ __launch_bounds__(256) void gemm_kernel(const float* __restrict__ A,
                                                   const float* __restrict__ B,
                                                   const float* __restrict__ bias,
                                                   float* __restrict__ C,
                                                   int M, int K, int N) {
  __shared__ float As[16][132];
  __shared__ float Bs[16][132];
  int tid = threadIdx.x;
  int tx = tid & 15;          // 0..15 -> col group
  int ty = tid >> 4;          // 0..15 -> row group
  int brow = blockIdx.x * 128;
  int bcol = blockIdx.y * 128;

  float acc[8][8];
#pragma unroll
  for (int i = 0; i < 8; ++i)
#pragma unroll
    for (int j = 0; j < 8; ++j) acc[i][j] = 0.f;

  for (int k0 = 0; k0 < K; k0 += 16) {
    // stage A tile (128 rows x 16 k), store transposed As[k][m]
#pragma unroll
    for (int li = 0; li < 2; ++li) {
      int idx = tid + li * 256;        // 0..511
      int r = idx >> 2;                // 0..127
      int kq = (idx & 3) << 2;         // 0,4,8,12
      int gr = brow + r;
      float4 v = make_float4(0.f, 0.f, 0.f, 0.f);
      if (gr < M) v = *(const float4*)&A[(size_t)gr * K + k0 + kq];
      As[kq + 0][r] = v.x;
      As[kq + 1][r] = v.y;
      As[kq + 2][r] = v.z;
      As[kq + 3][r] = v.w;
    }
    // stage B tile (16 k x 128 n)
#pragma unroll
    for (int li = 0; li < 2; ++li) {
      int idx = tid + li * 256;
      int kk = idx >> 5;               // 0..15
      int nq = (idx & 31) << 2;        // 0..124
      float4 v = *(const float4*)&B[(size_t)(k0 + kk) * N + bcol + nq];
      *(float4*)&Bs[kk][nq] = v;
    }
    __syncthreads();

#pragma unroll
    for (int kk = 0; kk < 16; ++kk) {
      float a[8], b[8];
      *(float4*)&a[0] = *(float4*)&As[kk][ty * 8];
      *(float4*)&a[4] = *(float4*)&As[kk][ty * 8 + 4];
      *(float4*)&b[0] = *(float4*)&Bs[kk][tx * 8];
      *(float4*)&b[4] = *(float4*)&Bs[kk][tx * 8 + 4];
#pragma unroll
      for (int i = 0; i < 8; ++i)
#pragma unroll
        for (int j = 0; j < 8; ++j) acc[i][j] += a[i] * b[j];
    }
    __syncthreads();
  }

  // epilogue
  float bv[8];
#pragma unroll
  for (int j = 0; j < 8; ++j)
    bv[j] = bias ? bias[bcol + tx * 8 + j] : 0.f;

#pragma unroll
  for (int i = 0; i < 8; ++i) {
    int row = brow + ty * 8 + i;
    if (row < M) {
      float4 o0, o1;
      o0.x = acc[i][0] + bv[0]; o0.y = acc[i][1] + bv[1];
      o0.z = acc[i][2] + bv[2]; o0.w = acc[i][3] + bv[3];
      o1.x = acc[i][4] + bv[4]; o1.y = acc[i][5] + bv[5];
      o1.z = acc[i][6] + bv[6]; o1.w = acc[i][7] + bv[7];
      *(float4*)&C[(size_t)row * N + bcol + tx * 8] = o0;
      *(float4*)&C[(size_t)row * N + bcol + tx * 8 + 4] = o1;
    }
  }
}

// ---------------- CSR SpMM, D=128, wave per row ----------------
// dst[r,:] = sum_e val[e]*src[col[e],:]  (+bias, relu optional)

__global__ __launch_bounds__(256) void spmm128_kernel(const int* __restrict__ row_ptr,
                                                      const int* __restrict__ ecol,
                                                      const float* __restrict__ evals,
                                                      const float* __restrict__ src,
                                                      float* __restrict__ dst,
                                                      const float* __restrict__ bias,
                                                      int relu, int nrows) {
  int lane = threadIdx.x & 63;
  int row = blockIdx.x * 4 + (threadIdx.x >> 6);
  if (row >= nrows) return;
  int s = row_ptr[row];
  int e = row_ptr[row + 1];
  const float2* src2 = (const float2*)src;
  float accx = 0.f, accy = 0.f;
  int i = s;
  for (; i + 4 <= e; i += 4) {
    int c0 = ecol[i], c1 = ecol[i + 1], c2 = ecol[i + 2], c3 = ecol[i + 3];
    float v0 = evals[i], v1 = evals[i + 1], v2 = evals[i + 2], v3 = evals[i + 3];
    float2 d0 = src2[(size_t)c0 * 64 + lane];
    float2 d1 = src2[(size_t)c1 * 64 + lane];
    float2 d2 = src2[(size_t)c2 * 64 + lane];
    float2 d3 = src2[(size_t)c3 * 64 + lane];
    accx += v0 * d0.x; accy += v0 * d0.y;
    accx += v1 * d1.x; accy += v1 * d1.y;
    accx += v2 * d2.x; accy += v2 * d2.y;
    accx += v3 * d3.x; accy += v3 * d3.y;
  }
  for (; i < e; ++i) {
    int c = ecol[i];
    float v = evals[i];
    float2 d = src2[(size_t)c * 64 + lane];
    accx += v * d.x; accy += v * d.y;
  }
  if (bias) { accx += bias[2 * lane]; accy += bias[2 * lane + 1]; }
  if (relu) { accx = fmaxf(accx, 0.f); accy = fmaxf(accy, 0.f); }
  float2 r; r.x = accx; r.y = accy;
  ((float2*)dst)[(size_t)row * 64 + lane] = r;
}

// ---------------- fold classifier weights: Wc = W2 @ cW, bc = cb + b2 @ cW ----------------

__global__ __launch_bounds__(256) void wc_kernel(const float* __restrict__ W2,
                                                 const float* __restrict__ b2,
                                                 const float* __restrict__ cW1,
                                                 const float* __restrict__ cb1,
                                                 const float* __restrict__ cW2,
                                                 const float* __restrict__ cb2,
                                                 float* __restrict__ Wc1, float* __restrict__ bc1,
                                                 float* __restrict__ Wc2, float* __restrict__ bc2) {
  int idx = blockIdx.x * 256 + threadIdx.x;   // 0..4095
  int set = idx >> 11;                        // 0 -> Wc1, 1 -> Wc2
  int e = idx & 2047;
  int i = e >> 4;                             // 0..127 (NHID row)
  int c = e & 15;
  const float* cw = set ? cW2 : cW1;
  float acc = 0.f;
  for (int k = 0; k < NFEAT; ++k)
    acc += W2[(size_t)i * NFEAT + k] * cw[k * NCLASS + c];
  (set ? Wc2 : Wc1)[e] = acc;
  if (idx < 32) {
    int s2 = idx >> 4, c2 = idx & 15;
    const float* cwb = s2 ? cW2 : cW1;
    float b = (s2 ? cb2 : cb1)[c2];
    for (int k = 0; k < NFEAT; ++k) b += b2[k] * cwb[k * NCLASS + c2];
    (s2 ? bc2 : bc1)[c2] = b;
  }
}

// ---------------- classifier: cls[r,:] = t3[row0+r,:] @ Wc + bc ----------------
// wave per row; lane: c = lane&15, kg = lane>>4 owns k in [kg*32, kg*32+32)

__global__ __launch_bounds__(256) void cls_kernel(const float* __restrict__ t3,
                                                  const float* __restrict__ Wc,
                                                  const float* __restrict__ bc,
                                                  float* __restrict__ outp,
                                                  int row0, int nrows) {
  int lane = threadIdx.x & 63;
  int wav = blockIdx.x * 4 + (threadIdx.x >> 6);
  int nw = gridDim.x * 4;
  int c = lane & 15;
  int kg = lane >> 4;
  float w[32];
#pragma unroll
  for (int j = 0; j < 32; ++j) w[j] = Wc[(kg * 32 + j) * NCLASS + c];
  float bcv = bc[c];
  for (int r = wav; r < nrows; r += nw) {
    const float4* rowp = (const float4*)&t3[(size_t)(row0 + r) * NHID + kg * 32];
    float acc = 0.f;
#pragma unroll
    for (int q = 0; q < 8; ++q) {
      float4 d = rowp[q];
      acc += d.x * w[q * 4 + 0] + d.y * w[q * 4 + 1] + d.z * w[q * 4 + 2] + d.w * w[q * 4 + 3];
    }
    acc += __shfl_xor(acc, 16);
    acc += __shfl_xor(acc, 32);
    if (lane < 16) outp[(size_t)r * NCLASS + lane] = acc + bcv;
  }
}

// ---------------- launch ----------------

extern "C" void kernel_launch(void* const* d_in, const int* in_sizes, int n_in,
                              void* d_out, int out_size, void* d_ws, size_t ws_size,
                              hipStream_t stream) {
  const float* x     = (const float*)d_in[0];
  const int*   arows = (const int*)d_in[1];
  const int*   acols = (const int*)d_in[2];
  const float* avals = (const float*)d_in[3];
  const float* W1    = (const float*)d_in[4];
  const float* b1    = (const float*)d_in[5];
  const float* W2    = (const float*)d_in[6];
  const float* b2    = (const float*)d_in[7];
  const float* cW1   = (const float*)d_in[8];
  const float* cb1   = (const float*)d_in[9];
  const float* cW2   = (const float*)d_in[10];
  const float* cb2   = (const float*)d_in[11];
  float* outp = (float*)d_out;

  char* ws = (char*)d_ws;
  size_t off = 0;
  auto alloc = [&](size_t bytes) -> void* {
    void* p = ws + off;
    off += (bytes + 255) & ~(size_t)255;
    return p;
  };
  float* B1     = (float*)alloc((size_t)N_NODES * NHID * 4);   // t1 / t3
  float* B2     = (float*)alloc((size_t)N_NODES * NHID * 4);   // h
  int*   ecol   = (int*)  alloc((size_t)N_EDGES * 4);
  float* evals  = (float*)alloc((size_t)N_EDGES * 4);
  int*   rowp   = (int*)  alloc((size_t)(N_NODES + 1) * 4);
  int*   cursor = (int*)  alloc((size_t)N_NODES * 4);
  int*   cnt    = (int*)  alloc((size_t)N_NODES * 4);
  int*   tmp    = (int*)  alloc((size_t)N_NODES * 4);
  int*   parts  = (int*)  alloc(512);
  float* Wc1    = (float*)alloc(NHID * NCLASS * 4);
  float* Wc2    = (float*)alloc(NHID * NCLASS * 4);
  float* bc1    = (float*)alloc(64);
  float* bc2    = (float*)alloc(64);

  // ---- CSR build ----
  zero_int_kernel<<<(N_NODES + 255) / 256, 256, 0, stream>>>(cnt, N_NODES);
  count_kernel<<<2048, 256, 0, stream>>>(arows, cnt, N_EDGES);
  int nchunk = (N_NODES + 1023) / 1024;  // 98
  scan1_kernel<<<nchunk, 1024, 0, stream>>>(cnt, tmp, parts, N_NODES);
  scan2_kernel<<<1, 128, 0, stream>>>(parts, nchunk);
  scan3_kernel<<<nchunk, 1024, 0, stream>>>(tmp, parts, rowp, cursor, N_NODES, N_EDGES);
  fill_kernel<<<2048, 256, 0, stream>>>(arows, acols, avals, cursor, ecol, evals, N_EDGES);

  // ---- t1 = x @ W1 ----
  gemm_kernel<<<dim3((N_NODES + 127) / 128, NHID / 128), 256, 0, stream>>>(
      x, W1, nullptr, B1, N_NODES, NFEAT, NHID);
  // ---- h = relu(A @ t1 + b1) ----
  spmm128_kernel<<<(N_NODES + 3) / 4, 256, 0, stream>>>(rowp, ecol, evals, B1, B2, b1, 1, N_NODES);
  // ---- t3 = A @ h ----
  spmm128_kernel<<<(N_NODES + 3) / 4, 256, 0, stream>>>(rowp, ecol, evals, B2, B1, nullptr, 0, N_NODES);
  // ---- out = t3 @ W2 + b2 ----
  gemm_kernel<<<dim3((N_NODES + 127) / 128, NFEAT / 128), 256, 0, stream>>>(
      B1, W2, b2, outp, N_NODES, NHID, NFEAT);
  // ---- folded classifier weights ----
  wc_kernel<<<16, 256, 0, stream>>>(W2, b2, cW1, cb1, cW2, cb2, Wc1, bc1, Wc2, bc2);
  // ---- classifiers ----
  cls_kernel<<<1024, 256, 0, stream>>>(B1, Wc1, bc1, outp + (size_t)N_NODES * NFEAT, 0, TEXT_CNT);
  cls_kernel<<<1024, 256, 0, stream>>>(B1, Wc2, bc2,
      outp + (size_t)N_NODES * NFEAT + (size_t)TEXT_CNT * NCLASS, TEXT_CNT, N_NODES - TEXT_CNT);
}